// Round 1
// baseline (236.306 us; speedup 1.0000x reference)
//
#include <hip/hip_runtime.h>
#include <hip/hip_bf16.h>

// out[256, 100000] = (inputs[256,256] @ features[100000,256]^T) * (1/0.07)
// bf16 MFMA (fp32 accum), memory-bound streaming over features + out.

typedef __attribute__((ext_vector_type(8)))  __bf16 bf16x8;   // 8 bf16 = 4 VGPRs
typedef __attribute__((ext_vector_type(4)))  float  floatx4;  // MFMA accum
typedef __attribute__((ext_vector_type(4)))  unsigned int uint4v;

#define NB 100000
#define KD 256
#define MB 256
#define BN 64
#define LDS_STRIDE 132   // dwords per feature row: 128 data + 4 pad (breaks pow2 bank stride)

union FragCast { uint4v u; bf16x8 f; };

__device__ __forceinline__ unsigned pk(float a, float b) {
  // packed f32->bf16 RNE (v_cvt_pk_bf16_f32)
  __hip_bfloat162 h = __float22bfloat162_rn(float2{a, b});
  union { __hip_bfloat162 h2; unsigned u; } cvt;
  cvt.h2 = h;
  return cvt.u;
}

__global__ __launch_bounds__(512, 4)
void sct_memory_gemm(const float* __restrict__ inputs,
                     const float* __restrict__ features,
                     float* __restrict__ out) {
  __shared__ unsigned lds[BN * LDS_STRIDE];   // 33792 B: features tile as bf16 pairs

  const int tid = threadIdx.x;
  const int n0 = blockIdx.x * BN;

  // ---- stage features tile [BN x KD] f32 -> bf16 -> LDS ----
  // chunk = 8 consecutive f32 (32 B global, 16 B LDS). 64 rows * 32 chunks = 2048
  // chunks; 4 per thread, lane-consecutive chunks for coalescing.
  #pragma unroll
  for (int i = 0; i < 4; ++i) {
    const int c  = i * 512 + tid;
    const int r  = c >> 5;        // row within tile
    const int ck = c & 31;        // 8-float chunk within row
    const int n  = n0 + r;
    float4 f0 = make_float4(0.f, 0.f, 0.f, 0.f), f1 = f0;
    if (n < NB) {
      const float4* p =
          reinterpret_cast<const float4*>(features + (size_t)n * KD + ck * 8);
      f0 = p[0];
      f1 = p[1];
    }
    uint4v w;
    w.x = pk(f0.x, f0.y); w.y = pk(f0.z, f0.w);
    w.z = pk(f1.x, f1.y); w.w = pk(f1.z, f1.w);
    *reinterpret_cast<uint4v*>(&lds[r * LDS_STRIDE + ck * 4]) = w;
  }

  // ---- A fragments: wave's 32 input rows, full K=256, from global (L2-hot) ----
  const int wave  = tid >> 6;
  const int lane  = tid & 63;
  const int lquad = lane >> 4;   // 0..3
  const int l16   = lane & 15;   // 0..15

  bf16x8 afrag[2][8];            // [m-subtile][k-step] = 64 VGPRs
  #pragma unroll
  for (int s = 0; s < 2; ++s) {
    const int m = wave * 32 + s * 16 + l16;           // < 256
    const float* arow = inputs + (size_t)m * KD + lquad * 8;
    #pragma unroll
    for (int t = 0; t < 8; ++t) {
      const float4* p = reinterpret_cast<const float4*>(arow + t * 32);
      const float4 a0 = p[0], a1 = p[1];
      FragCast fc;
      fc.u.x = pk(a0.x, a0.y); fc.u.y = pk(a0.z, a0.w);
      fc.u.z = pk(a1.x, a1.y); fc.u.w = pk(a1.z, a1.w);
      afrag[s][t] = fc.f;
    }
  }

  __syncthreads();

  // ---- MFMA: 2 m-subtiles x 4 n-subtiles, K unrolled in 8 steps of 32 ----
  floatx4 acc[2][4];
  #pragma unroll
  for (int s = 0; s < 2; ++s)
    #pragma unroll
    for (int nt = 0; nt < 4; ++nt)
      acc[s][nt] = floatx4{0.f, 0.f, 0.f, 0.f};

  #pragma unroll
  for (int t = 0; t < 8; ++t) {
    bf16x8 bfrag[4];
    #pragma unroll
    for (int nt = 0; nt < 4; ++nt) {
      const int row = nt * 16 + l16;  // feature row within tile = N col
      FragCast fc;
      fc.u = *reinterpret_cast<const uint4v*>(
          &lds[row * LDS_STRIDE + t * 16 + lquad * 4]);
      bfrag[nt] = fc.f;
    }
    #pragma unroll
    for (int s = 0; s < 2; ++s)
      #pragma unroll
      for (int nt = 0; nt < 4; ++nt)
        acc[s][nt] = __builtin_amdgcn_mfma_f32_16x16x32_bf16(
            afrag[s][t], bfrag[nt], acc[s][nt], 0, 0, 0);
  }

  // ---- store: D col = lane&15 (N, coalesced 64B segs), row = quad*4 + reg ----
  const float scale = 1.0f / 0.07f;
  #pragma unroll
  for (int s = 0; s < 2; ++s) {
    const int mbase = wave * 32 + s * 16 + lquad * 4;
    #pragma unroll
    for (int nt = 0; nt < 4; ++nt) {
      const int n = n0 + nt * 16 + l16;
      if (n < NB) {
        #pragma unroll
        for (int r = 0; r < 4; ++r) {
          out[(size_t)(mbase + r) * NB + n] = acc[s][nt][r] * scale;
        }
      }
    }
  }
}

extern "C" void kernel_launch(void* const* d_in, const int* in_sizes, int n_in,
                              void* d_out, int out_size, void* d_ws, size_t ws_size,
                              hipStream_t stream) {
  const float* inputs   = (const float*)d_in[0];  // [256, 256] f32
  // d_in[1] = indexes (unused by forward output)
  const float* features = (const float*)d_in[2];  // [100000, 256] f32
  // d_in[3] = momentum (unused)
  float* out = (float*)d_out;                     // [256, 100000] f32

  const int grid = (NB + BN - 1) / BN;            // 1563
  sct_memory_gemm<<<grid, 512, 0, stream>>>(inputs, features, out);
}

// Round 2
// 200.238 us; speedup vs baseline: 1.1801x; 1.1801x over previous
//
#include <hip/hip_runtime.h>
#include <hip/hip_bf16.h>

// out[256, 100000] = (inputs[256,256] @ features[100000,256]^T) / 0.07
// Persistent tile-loop blocks: 256 blocks x 1024 threads, 1 block/CU.
// Each block owns n-tiles {b, b+256, b+512, ...} of width 64 and loops over
// them with register-held prefetch of the next features tile across the
// barrier, so the vmcnt(0) barrier drain hides a full compute phase of HBM
// latency. A (inputs) is loaded+converted once per block (scale folded in).

typedef __attribute__((ext_vector_type(8))) __bf16 bf16x8;   // 4 VGPRs
typedef __attribute__((ext_vector_type(4))) float  floatx4;  // MFMA acc
typedef __attribute__((ext_vector_type(4))) unsigned int uint4v;

#define NB 100000
#define KD 256
#define BN 64
#define NTILES 1563           // ceil(NB / BN)
#define GRID 256
#define LDS_STRIDE 132        // dwords/row: 128 data + 4 pad

union FragCast { uint4v u; bf16x8 f; };

__device__ __forceinline__ unsigned pk(float a, float b) {
  // v_cvt_pk_bf16_f32 (RNE)
  __hip_bfloat162 h = __float22bfloat162_rn(float2{a, b});
  union { __hip_bfloat162 h2; unsigned u; } c; c.h2 = h; return c.u;
}

__global__ __launch_bounds__(1024, 4)
void sct_gemm(const float* __restrict__ inputs,
              const float* __restrict__ features,
              float* __restrict__ out) {
  __shared__ unsigned lds[BN * LDS_STRIDE];   // 33792 B bf16 B-tile

  const int tid  = threadIdx.x;
  const int ws   = tid >> 6;     // wave 0..15 -> m-subtile
  const int lane = tid & 63;
  const int quad = lane >> 4;
  const int l16  = lane & 15;

  const int b = blockIdx.x;
  const int ntiles = (NTILES - b + GRID - 1) / GRID;

  // staging decomposition: chunk c = i*1024 + tid; row r = c>>5, 8-float
  // chunk ck = c&31 within the row (coalesced across consecutive tid).
  const int srow0 = tid >> 5,            sck0 = tid & 31;
  const int srow1 = (1024 + tid) >> 5,   sck1 = tid & 31;

  // ---- prefetch tile 0 into registers ----
  float4 pf0a, pf0b, pf1a, pf1b;
  {
    const int n0 = b * BN;
    pf0a = pf0b = pf1a = pf1b = make_float4(0.f, 0.f, 0.f, 0.f);
    if (n0 + srow0 < NB) {
      const float4* p = (const float4*)(features + (size_t)(n0 + srow0) * KD + sck0 * 8);
      pf0a = p[0]; pf0b = p[1];
    }
    if (n0 + srow1 < NB) {
      const float4* p = (const float4*)(features + (size_t)(n0 + srow1) * KD + sck1 * 8);
      pf1a = p[0]; pf1b = p[1];
    }
  }

  // ---- A fragments (once per block), scale folded in ----
  const float scale = 1.0f / 0.07f;
  bf16x8 afrag[8];                         // 32 VGPRs
  {
    const float* arow = inputs + (ws * 16 + l16) * KD + quad * 8;
    #pragma unroll
    for (int t = 0; t < 8; ++t) {
      const float4* p = (const float4*)(arow + t * 32);
      const float4 a0 = p[0], a1 = p[1];
      FragCast fc;
      fc.u.x = pk(a0.x * scale, a0.y * scale);
      fc.u.y = pk(a0.z * scale, a0.w * scale);
      fc.u.z = pk(a1.x * scale, a1.y * scale);
      fc.u.w = pk(a1.z * scale, a1.w * scale);
      afrag[t] = fc.f;
    }
  }

  // per-lane 32-bit store base: m = ws*16 + quad*4 (+r), col l16
  const unsigned obase = (unsigned)((ws * 16 + quad * 4) * NB + l16);

  for (int it = 0; it < ntiles; ++it) {
    const int n0 = (b + it * GRID) * BN;

    __syncthreads();   // all waves done reading lds from previous tile
                       // (vmcnt drain here also completes the prefetch loads)

    // ---- stage current tile: convert prefetched f32 -> bf16 -> LDS ----
    {
      uint4v w;
      w.x = pk(pf0a.x, pf0a.y); w.y = pk(pf0a.z, pf0a.w);
      w.z = pk(pf0b.x, pf0b.y); w.w = pk(pf0b.z, pf0b.w);
      *(uint4v*)&lds[srow0 * LDS_STRIDE + sck0 * 4] = w;
      w.x = pk(pf1a.x, pf1a.y); w.y = pk(pf1a.z, pf1a.w);
      w.z = pk(pf1b.x, pf1b.y); w.w = pk(pf1b.z, pf1b.w);
      *(uint4v*)&lds[srow1 * LDS_STRIDE + sck1 * 4] = w;
    }
    __syncthreads();

    // ---- issue prefetch for next tile (consumed next iteration) ----
    if (it + 1 < ntiles) {
      const int nn0 = (b + (it + 1) * GRID) * BN;
      pf0a = pf0b = pf1a = pf1b = make_float4(0.f, 0.f, 0.f, 0.f);
      if (nn0 + srow0 < NB) {
        const float4* p = (const float4*)(features + (size_t)(nn0 + srow0) * KD + sck0 * 8);
        pf0a = p[0]; pf0b = p[1];
      }
      if (nn0 + srow1 < NB) {
        const float4* p = (const float4*)(features + (size_t)(nn0 + srow1) * KD + sck1 * 8);
        pf1a = p[0]; pf1b = p[1];
      }
    }

    // ---- MFMA: 1 m-subtile x 4 n-subtiles, K=256 in 8 steps ----
    floatx4 acc[4];
    #pragma unroll
    for (int nt = 0; nt < 4; ++nt) acc[nt] = floatx4{0.f, 0.f, 0.f, 0.f};

    #pragma unroll
    for (int t = 0; t < 8; ++t) {
      #pragma unroll
      for (int nt = 0; nt < 4; ++nt) {
        FragCast fc;
        fc.u = *(const uint4v*)&lds[(nt * 16 + l16) * LDS_STRIDE + t * 16 + quad * 4];
        acc[nt] = __builtin_amdgcn_mfma_f32_16x16x32_bf16(afrag[t], fc.f, acc[nt], 0, 0, 0);
      }
    }

    // ---- store (scale already folded into A) ----
    #pragma unroll
    for (int nt = 0; nt < 4; ++nt) {
      const int n = n0 + nt * 16 + l16;
      if (n < NB) {
        const unsigned col = obase + (unsigned)(n0 + nt * 16);
        #pragma unroll
        for (int r = 0; r < 4; ++r)
          out[col + (unsigned)(r * NB)] = acc[nt][r];
      }
    }
  }
}

extern "C" void kernel_launch(void* const* d_in, const int* in_sizes, int n_in,
                              void* d_out, int out_size, void* d_ws, size_t ws_size,
                              hipStream_t stream) {
  const float* inputs   = (const float*)d_in[0];  // [256,256] f32
  // d_in[1] = indexes (unused), d_in[3] = momentum (unused)
  const float* features = (const float*)d_in[2];  // [100000,256] f32
  float* out = (float*)d_out;                     // [256,100000] f32

  sct_gemm<<<GRID, 1024, 0, stream>>>(inputs, features, out);
}